// Round 8
// baseline (262.212 us; speedup 1.0000x reference)
//
#include <hip/hip_runtime.h>
#include <hip/hip_fp16.h>

// ---------------------------------------------------------------------------
// InversePerspectiveProjection. R8:
//   k1 transpose: images (N,C,Hi,Wi) fp32 -> imgT (N,Hi*Wi,C) fp16.
//                 NOW 4 tiles per block, register-prefetch pipelined across
//                 the barrier (R5-R7 version was latency/barrier-bound:
//                 4 loads -> sync -> 4 stores per 16 KB tile).
//   k2 fused    : unchanged from R7 (at its 512 B/(pt,cam) traffic floor).
// ---------------------------------------------------------------------------

#define N_IMG 6
#define C_CH  64
#define HI    224
#define WI    400
#define HW    (HI * WI)          // 89600
#define D_RES 8
#define H_RES 128
#define W_RES 128
#define P_TOT (D_RES * H_RES * W_RES)   // 131072
#define VOX   0.4f
#define ROW8  (WI * 16)          // 8B units per image row (6400)
#define TPB   4                  // tiles per transpose block

// ---------------- k1: pipelined transpose (N,C,HW) fp32 -> (N,HW,C) fp16 ---
__global__ __launch_bounds__(256) void transpose_k(const float* __restrict__ in,
                                                   __half* __restrict__ outh) {
    __shared__ float tile[64 * 65];           // [c][pix], pitch 65
    int b     = blockIdx.x;                   // 2100 blocks
    int n     = b / (1400 / TPB);             // 350 groups per image
    int tile0 = (b % (1400 / TPB)) * TPB;
    int t     = threadIdx.x;
    int col4  = t & 15;
    int crow  = t >> 4;

    const float* inp = in + (size_t)n * C_CH * HW + 4 * col4;
    struct __align__(8) H4 { __half2 a, b; };
    H4* outp = (H4*)outh;
    int ch4  = 4 * (t & 15);
    int prow = t >> 4;

    float4 v[4];
    // prologue: load tile 0
#pragma unroll
    for (int i = 0; i < 4; ++i)
        v[i] = *(const float4*)(inp + (size_t)(i * 16 + crow) * HW + tile0 * 64);

    for (int tt = 0; tt < TPB; ++tt) {
        int s_base = (tile0 + tt) * 64;
        // regs -> LDS
#pragma unroll
        for (int i = 0; i < 4; ++i) {
            int c = i * 16 + crow;
            tile[c * 65 + 4 * col4 + 0] = v[i].x;
            tile[c * 65 + 4 * col4 + 1] = v[i].y;
            tile[c * 65 + 4 * col4 + 2] = v[i].z;
            tile[c * 65 + 4 * col4 + 3] = v[i].w;
        }
        __syncthreads();
        // prefetch next tile while this tile is packed+stored
        if (tt + 1 < TPB) {
#pragma unroll
            for (int i = 0; i < 4; ++i)
                v[i] = *(const float4*)(inp + (size_t)(i * 16 + crow) * HW
                                        + (s_base + 64));
        }
        // LDS -> packed fp16 -> global (coalesced 512 B/wave)
#pragma unroll
        for (int i = 0; i < 4; ++i) {
            int pix = i * 16 + prow;
            H4 pk;
            pk.a = __floats2half2_rn(tile[(ch4 + 0) * 65 + pix],
                                     tile[(ch4 + 1) * 65 + pix]);
            pk.b = __floats2half2_rn(tile[(ch4 + 2) * 65 + pix],
                                     tile[(ch4 + 3) * 65 + pix]);
            outp[(size_t)(n * HW + s_base + pix) * 16 + (ch4 >> 2)] = pk;
        }
        __syncthreads();                      // tile reads done -> safe reuse
    }
}

// ---------------- geometry for one (point, image) --------------------------
// Weights remapped onto clamped 2x2 block at (by..by+1, bx..bx+1), *1/6,
// zeros for invalid/masked. oout = 8B-unit offset of block base (by,bx).
__device__ __forceinline__ void make_rec(int p, int n,
                                         const float* __restrict__ Kmat,
                                         const float* __restrict__ Rmat,
                                         const float* __restrict__ Tvec,
                                         float4& wout, int& oout) {
#pragma clang fp contract(off)               // match numpy rounding (mask boundary)
    // flat p is meshgrid (H,W,D) order: p = ih*1024 + iw*8 + id
    int ih = p >> 10;
    int iw = (p >> 3) & (W_RES - 1);
    int id = p & (D_RES - 1);

    float px = ((float)ih - 63.5f) * VOX;
    float py = ((float)iw - 63.5f) * VOX;
    float pz = ((float)id - 3.5f) * VOX;

    const float* R = Rmat + n * 9;
    const float* K = Kmat + n * 9;
    const float* T = Tvec + n * 3;

    float cx = px * R[0] + py * R[1] + pz * R[2] + T[0];
    float cy = px * R[3] + py * R[4] + pz * R[5] + T[1];
    float cz = px * R[6] + py * R[7] + pz * R[8] + T[2];

    float pix0 = cx * K[0] + cy * K[1] + cz * K[2];
    float pix1 = cx * K[3] + cy * K[4] + cz * K[5];
    float pix2 = cx * K[6] + cy * K[7] + cz * K[8];

    if (pix2 < 0.1f) {
        wout = make_float4(0.0f, 0.0f, 0.0f, 0.0f);
        oout = n * (HW * 16);
        return;
    }
    float u = pix0 / pix2;
    float v = pix1 / pix2;
    float g0 = 2.0f * v / 223.0f - 1.0f;
    float g1 = 2.0f * u / 399.0f - 1.0f;
    float xs = ((g0 + 1.0f) * 400.0f - 1.0f) * 0.5f;
    float ys = ((g1 + 1.0f) * 224.0f - 1.0f) * 0.5f;
    xs = fminf(fmaxf(xs, -10.0f), 410.0f);
    ys = fminf(fmaxf(ys, -10.0f), 234.0f);
    float x0f = floorf(xs), y0f = floorf(ys);
    float wx = xs - x0f, wy = ys - y0f;
    int x0 = (int)x0f, y0 = (int)y0f;
    int x1 = x0 + 1, y1 = y0 + 1;

    int bx = min(max(x0, 0), WI - 2);
    int by = min(max(y0, 0), HI - 2);
    float wxA = (bx     == x0) ? (1.0f - wx) : ((bx     == x1) ? wx : 0.0f);
    float wxB = (bx + 1 == x0) ? (1.0f - wx) : ((bx + 1 == x1) ? wx : 0.0f);
    float wyA = (by     == y0) ? (1.0f - wy) : ((by     == y1) ? wy : 0.0f);
    float wyB = (by + 1 == y0) ? (1.0f - wy) : ((by + 1 == y1) ? wy : 0.0f);

    const float inv6 = 1.0f / 6.0f;
    wout.x = wxA * wyA * inv6;                // corner 0: row by  , px bx
    wout.y = wxB * wyA * inv6;                // corner 1: row by  , px bx+1
    wout.z = wxA * wyB * inv6;                // corner 2: row by+1, px bx
    wout.w = wxB * wyB * inv6;                // corner 3: row by+1, px bx+1
    oout = n * (HW * 16) + (by * WI + bx) * 16;   // 8B units
}

// ---------------- k2: fused geometry + gather + transpose-write ------------
__global__ __launch_bounds__(256) void sample_k(const float* __restrict__ Kmat,
                                                const float* __restrict__ Rmat,
                                                const float* __restrict__ Tvec,
                                                const __half* __restrict__ imgT,
                                                float* __restrict__ out) {
    __shared__ float swt[64 * N_IMG * 4];     // 6 KB weights (float[4]/rec)
    __shared__ int   sof[64 * N_IMG];         // 1.5 KB block-base offsets
    __shared__ float sout[64 * 66];           // 16.9 KB acc tile

    int t = threadIdx.x;
    // XCD-aware swizzle: each XCD gets a contiguous ih-slab (L2 locality)
    int bid    = ((blockIdx.x & 7) << 8) | (blockIdx.x >> 3);   // 2048 = 8*256
    int p_base = bid * 64;

    for (int i = t; i < 64 * N_IMG; i += 256) {
        float4 w; int o;
        make_rec(p_base + i / N_IMG, i % N_IMG, Kmat, Rmat, Tvec, w, o);
        *(float4*)&swt[i * 4] = w;
        sof[i] = o;
    }
    __syncthreads();

    // gather: ONE dwordx2 wave-load = whole 512 B 2x2x64ch corner block.
    struct __align__(8) H22 { __half2 a, b; };
    const H22* img8 = (const H22*)imgT;

    int lane   = t & 63;
    int wv     = t >> 6;                      // wave 0..3 -> points wv*16..+15
    int corner = lane >> 4;                   // 0..3
    int lofs   = (lane >> 5) * ROW8 + ((lane >> 4) & 1) * 16 + (lane & 15);

#pragma unroll 4
    for (int j = 0; j < 16; ++j) {
        int pl = wv * 16 + j;                 // block-local point
        float ax = 0.0f, ay = 0.0f, az = 0.0f, aw = 0.0f;
#pragma unroll
        for (int n = 0; n < N_IMG; ++n) {
            int   ri = pl * N_IMG + n;
            float w  = swt[ri * 4 + corner];  // broadcast in 16-lane groups
            H22   v  = img8[sof[ri] + lofs];  // 512 B wave-load
            float2 f0 = __half22float2(v.a);
            float2 f1 = __half22float2(v.b);
            ax = fmaf(w, f0.x, ax);
            ay = fmaf(w, f0.y, ay);
            az = fmaf(w, f1.x, az);
            aw = fmaf(w, f1.y, aw);
        }
        // corner reduction: sum lanes {l, l^16, l^32, l^48}
        ax += __shfl_xor(ax, 16, 64);  ay += __shfl_xor(ay, 16, 64);
        az += __shfl_xor(az, 16, 64);  aw += __shfl_xor(aw, 16, 64);
        ax += __shfl_xor(ax, 32, 64);  ay += __shfl_xor(ay, 32, 64);
        az += __shfl_xor(az, 32, 64);  aw += __shfl_xor(aw, 32, 64);
        if (lane < 16) {                      // lane owns channels 4*lane..+3
            *(float2*)&sout[pl * 66 + lane * 4]     = make_float2(ax, ay);
            *(float2*)&sout[pl * 66 + lane * 4 + 2] = make_float2(az, aw);
        }
    }
    __syncthreads();

    // output: out[c*P + p], lane = point -> 256 B coalesced stores
    int csub = t >> 6;
#pragma unroll
    for (int i = 0; i < 16; ++i) {
        int c = csub * 16 + i;
        out[(size_t)c * P_TOT + p_base + lane] = sout[lane * 66 + c];
    }
}

// ---------------------------------------------------------------------------
extern "C" void kernel_launch(void* const* d_in, const int* in_sizes, int n_in,
                              void* d_out, int out_size, void* d_ws, size_t ws_size,
                              hipStream_t stream) {
    const float* images = (const float*)d_in[0];
    const float* intr   = (const float*)d_in[1];
    const float* rot    = (const float*)d_in[2];
    const float* trans  = (const float*)d_in[3];

    __half* imgT = (__half*)d_ws;             // 6*89600*64*2 B = 68.8 MB
    float*  outp = (float*)d_out;

    transpose_k<<<N_IMG * (1400 / TPB), 256, 0, stream>>>(images, imgT);
    sample_k<<<P_TOT / 64, 256, 0, stream>>>(intr, rot, trans, imgT, outp);
}

// Round 9
// 256.906 us; speedup vs baseline: 1.0207x; 1.0207x over previous
//
#include <hip/hip_runtime.h>
#include <hip/hip_fp16.h>

// ---------------------------------------------------------------------------
// InversePerspectiveProjection. R9 = R6 (best measured, 257.6 µs) + NT stores
// on the final output writes.
//   k1 transpose: images (N,C,Hi,Wi) fp32 -> imgT (N,Hi*Wi,C) fp16
//   k2 fused    : geometry emits per-(point,cam) {4 remapped weights, 1 row
//                 base}; gather = 2 contiguous 256 B wave-loads per (pt,cam)
//                 (row pair), cross-half shfl reduce, LDS transpose ->
//                 coalesced (C,P) fp32 NT stores. XCD-aware block swizzle.
// Established floors (R7/R8 single-variable tests, both neutral):
//   - sample: 512 B/(pt,cam) = 4 x 128 B lines is the minimum line traffic.
//   - transpose: BW-bound (~344 MB HBM-equivalent), not latency-bound.
// Fixed harness overhead (550 MB ws poison + restores) dominates dur_us.
// ---------------------------------------------------------------------------

#define N_IMG 6
#define C_CH  64
#define HI    224
#define WI    400
#define HW    (HI * WI)          // 89600
#define D_RES 8
#define H_RES 128
#define W_RES 128
#define P_TOT (D_RES * H_RES * W_RES)   // 131072
#define VOX   0.4f
#define ROWH2 (WI * 32)          // half2 units per image row (12800)

// ---------------- k1: transpose+convert (N,C,HW) fp32 -> (N,HW,C) fp16 -----
__global__ __launch_bounds__(256) void transpose_k(const float* __restrict__ in,
                                                   __half* __restrict__ outh) {
    __shared__ float tile[64 * 65];          // [c][pix], row pitch 65
    int b      = blockIdx.x;
    int n      = b / 1400;                    // HW/64 = 1400 tiles per image
    int s_base = (b % 1400) * 64;
    int t    = threadIdx.x;
    int col4 = t & 15;                        // pixel quad within tile
    int crow = t >> 4;                        // 0..15

    const float* inp = in + (size_t)n * C_CH * HW + s_base;
#pragma unroll
    for (int i = 0; i < 4; ++i) {
        int c = i * 16 + crow;
        const float4 v = *(const float4*)(inp + (size_t)c * HW + 4 * col4); // 16B aligned
        tile[c * 65 + 4 * col4 + 0] = v.x;
        tile[c * 65 + 4 * col4 + 1] = v.y;
        tile[c * 65 + 4 * col4 + 2] = v.z;
        tile[c * 65 + 4 * col4 + 3] = v.w;
    }
    __syncthreads();

    // write: per pixel 64ch * 2B = 128 B; thread covers 4 ch = one 8 B store
    struct __align__(8) H4 { __half2 a, b; };
    int ch4 = 4 * (t & 15);
    H4* outp = (H4*)outh;
#pragma unroll
    for (int i = 0; i < 4; ++i) {
        int pix = i * 16 + (t >> 4);
        H4 pk;
        pk.a = __floats2half2_rn(tile[(ch4 + 0) * 65 + pix],
                                 tile[(ch4 + 1) * 65 + pix]);
        pk.b = __floats2half2_rn(tile[(ch4 + 2) * 65 + pix],
                                 tile[(ch4 + 3) * 65 + pix]);
        outp[(size_t)(n * HW + s_base + pix) * 16 + (ch4 >> 2)] = pk;
    }
}

// ---------------- geometry for one (point, image) --------------------------
// Emits weights remapped onto the clamped 2x2 block at (by..by+1, bx..bx+1):
//   wout = inv6 * (wxA*wyA, wxB*wyA, wxA*wyB, wxB*wyB), zeros for invalid/mask
//   oout = half2-unit offset of (by, bx) pixel block.
__device__ __forceinline__ void make_rec(int p, int n,
                                         const float* __restrict__ Kmat,
                                         const float* __restrict__ Rmat,
                                         const float* __restrict__ Tvec,
                                         float4& wout, int& oout) {
#pragma clang fp contract(off)               // match numpy rounding (mask boundary)
    // flat p is meshgrid (H,W,D) order: p = ih*1024 + iw*8 + id
    int ih = p >> 10;
    int iw = (p >> 3) & (W_RES - 1);
    int id = p & (D_RES - 1);

    float px = ((float)ih - 63.5f) * VOX;
    float py = ((float)iw - 63.5f) * VOX;
    float pz = ((float)id - 3.5f) * VOX;

    const float* R = Rmat + n * 9;
    const float* K = Kmat + n * 9;
    const float* T = Tvec + n * 3;

    float cx = px * R[0] + py * R[1] + pz * R[2] + T[0];
    float cy = px * R[3] + py * R[4] + pz * R[5] + T[1];
    float cz = px * R[6] + py * R[7] + pz * R[8] + T[2];

    float pix0 = cx * K[0] + cy * K[1] + cz * K[2];
    float pix1 = cx * K[3] + cy * K[4] + cz * K[5];
    float pix2 = cx * K[6] + cy * K[7] + cz * K[8];

    if (pix2 < 0.1f) {
        wout = make_float4(0.0f, 0.0f, 0.0f, 0.0f);
        oout = n * (HW * 32);
        return;
    }
    float u = pix0 / pix2;
    float v = pix1 / pix2;
    float g0 = 2.0f * v / 223.0f - 1.0f;
    float g1 = 2.0f * u / 399.0f - 1.0f;
    float xs = ((g0 + 1.0f) * 400.0f - 1.0f) * 0.5f;
    float ys = ((g1 + 1.0f) * 224.0f - 1.0f) * 0.5f;
    xs = fminf(fmaxf(xs, -10.0f), 410.0f);
    ys = fminf(fmaxf(ys, -10.0f), 234.0f);
    float x0f = floorf(xs), y0f = floorf(ys);
    float wx = xs - x0f, wy = ys - y0f;
    int x0 = (int)x0f, y0 = (int)y0f;
    int x1 = x0 + 1, y1 = y0 + 1;

    int bx = min(max(x0, 0), WI - 2);
    int by = min(max(y0, 0), HI - 2);
    // weight of pixel q: (q==x0 ? 1-wx : q==x1 ? wx : 0) — folds validity+clamp
    float wxA = (bx     == x0) ? (1.0f - wx) : ((bx     == x1) ? wx : 0.0f);
    float wxB = (bx + 1 == x0) ? (1.0f - wx) : ((bx + 1 == x1) ? wx : 0.0f);
    float wyA = (by     == y0) ? (1.0f - wy) : ((by     == y1) ? wy : 0.0f);
    float wyB = (by + 1 == y0) ? (1.0f - wy) : ((by + 1 == y1) ? wy : 0.0f);

    const float inv6 = 1.0f / 6.0f;
    wout.x = wxA * wyA * inv6;                // row by  , pixel bx
    wout.y = wxB * wyA * inv6;                // row by  , pixel bx+1
    wout.z = wxA * wyB * inv6;                // row by+1, pixel bx
    wout.w = wxB * wyB * inv6;                // row by+1, pixel bx+1
    oout = n * (HW * 32) + (by * WI + bx) * 32;
}

// ---------------- k2: fused geometry + gather + transpose-write ------------
__global__ __launch_bounds__(256) void sample_k(const float* __restrict__ Kmat,
                                                const float* __restrict__ Rmat,
                                                const float* __restrict__ Tvec,
                                                const __half2* __restrict__ imgT2,
                                                float* __restrict__ out) {
    __shared__ float4 swt[64 * N_IMG];        // 6 KB weights
    __shared__ int    sof[64 * N_IMG];        // 1.5 KB row-base offsets
    __shared__ float  sout[64 * 66];          // 16.9 KB acc tile

    int t = threadIdx.x;
    // XCD-aware swizzle: each XCD gets a contiguous ih-slab (L2 locality)
    int bid    = ((blockIdx.x & 7) << 8) | (blockIdx.x >> 3);   // 2048 = 8*256
    int p_base = bid * 64;

    for (int i = t; i < 64 * N_IMG; i += 256) {
        float4 w; int o;
        make_rec(p_base + i / N_IMG, i % N_IMG, Kmat, Rmat, Tvec, w, o);
        swt[i] = w;
        sof[i] = o;
    }
    __syncthreads();

    // gather: one point per FULL wave; a row pair = 2 contiguous 256 B loads.
    // lane = (pixel half)*32 + channel-pair: imgT2[o + lane] covers bx,bx+1.
    int lane = t & 63;
    int wv   = t >> 6;                        // wave 0..3 -> points wv*16..+15
    int hi   = lane >> 5;                     // 0: pixel bx, 1: pixel bx+1

#pragma unroll 4
    for (int j = 0; j < 16; ++j) {
        int pl = wv * 16 + j;                 // block-local point
        float accx = 0.0f, accy = 0.0f;
#pragma unroll
        for (int n = 0; n < N_IMG; ++n) {
            float4 wt = swt[pl * N_IMG + n];  // broadcast ds_read_b128
            int    o  = sof[pl * N_IMG + n];
            float2 r0 = __half22float2(imgT2[o + lane]);          // row by
            float2 r1 = __half22float2(imgT2[o + ROWH2 + lane]);  // row by+1
            float w0 = hi ? wt.y : wt.x;
            float w1 = hi ? wt.w : wt.z;
            accx = fmaf(w0, r0.x, accx);  accy = fmaf(w0, r0.y, accy);
            accx = fmaf(w1, r1.x, accx);  accy = fmaf(w1, r1.y, accy);
        }
        accx += __shfl_xor(accx, 32, 64);     // combine the two pixel halves
        accy += __shfl_xor(accy, 32, 64);
        if (hi == 0)
            *(float2*)&sout[pl * 66 + 2 * (lane & 31)] = make_float2(accx, accy);
    }
    __syncthreads();

    // output: out[c*P + p], lane = point -> 256 B coalesced NT stores
    // (out is never re-read: bypass L2 so the epilogue doesn't evict
    //  gather-resident imgT lines)
    int csub = t >> 6;
#pragma unroll
    for (int i = 0; i < 16; ++i) {
        int c = csub * 16 + i;
        __builtin_nontemporal_store(sout[lane * 66 + c],
                                    &out[(size_t)c * P_TOT + p_base + lane]);
    }
}

// ---------------------------------------------------------------------------
extern "C" void kernel_launch(void* const* d_in, const int* in_sizes, int n_in,
                              void* d_out, int out_size, void* d_ws, size_t ws_size,
                              hipStream_t stream) {
    const float* images = (const float*)d_in[0];
    const float* intr   = (const float*)d_in[1];
    const float* rot    = (const float*)d_in[2];
    const float* trans  = (const float*)d_in[3];

    __half* imgT = (__half*)d_ws;             // 6*89600*64*2 B = 68.8 MB
    float*  outp = (float*)d_out;

    transpose_k<<<N_IMG * (HW / 64), 256, 0, stream>>>(images, imgT);
    sample_k<<<P_TOT / 64, 256, 0, stream>>>(intr, rot, trans,
                                             (const __half2*)imgT, outp);
}